// Round 17
// baseline (1746.512 us; speedup 1.0000x reference)
//
#include <hip/hip_runtime.h>
#include <hip/hip_bf16.h>
#include <math.h>

// Shapes (fixed): B=4, S=512, PH=4096, N=16384, D=1024, G=128, H=8, L=4, FF=4096, GS=32, HD=128

typedef __bf16 bf16x8_t __attribute__((ext_vector_type(8)));
typedef float  f32x4_t  __attribute__((ext_vector_type(4)));

__device__ __forceinline__ float wredsum(float v){
#pragma unroll
  for (int o = 32; o; o >>= 1) v += __shfl_down(v, o, 64);
  return v;  // valid in lane 0
}

__device__ __forceinline__ bf16x8_t pack8(float4 a, float4 b){
  bf16x8_t v;
  v[0]=(__bf16)a.x; v[1]=(__bf16)a.y; v[2]=(__bf16)a.z; v[3]=(__bf16)a.w;
  v[4]=(__bf16)b.x; v[5]=(__bf16)b.y; v[6]=(__bf16)b.z; v[7]=(__bf16)b.w;
  return v;
}

__device__ __forceinline__ void gload16(const void* g, void* l){
  __builtin_amdgcn_global_load_lds((const __attribute__((address_space(1))) unsigned int*)g,
                                   (__attribute__((address_space(3))) unsigned int*)l, 16, 0, 0);
}

// f32 wave-max via ds_swizzle xor stages + cross-half shfl (validated R14)
__device__ __forceinline__ float wmax_f32(float m){
  m = fmaxf(m, __int_as_float(__builtin_amdgcn_ds_swizzle(__float_as_int(m), 0x041F)));
  m = fmaxf(m, __int_as_float(__builtin_amdgcn_ds_swizzle(__float_as_int(m), 0x081F)));
  m = fmaxf(m, __int_as_float(__builtin_amdgcn_ds_swizzle(__float_as_int(m), 0x101F)));
  m = fmaxf(m, __int_as_float(__builtin_amdgcn_ds_swizzle(__float_as_int(m), 0x201F)));
  m = fmaxf(m, __int_as_float(__builtin_amdgcn_ds_swizzle(__float_as_int(m), 0x401F)));
  m = fmaxf(m, __shfl_xor(m, 32, 64));
  return m;
}

// ---------------------------------------------------------------- fused front-end (validated R14/R16)
__global__ __launch_bounds__(1024) void fused_front(
  const float* __restrict__ pc, float* __restrict__ centers,
  const float* __restrict__ agg, const float* __restrict__ spw,
  const float* __restrict__ spb, float* __restrict__ x,
  const float* __restrict__ inw, const float* __restrict__ outw,
  const float* __restrict__ w1, const float* __restrict__ w2,
  __bf16* __restrict__ wbf)
{
  const int bid = blockIdx.x;
  const int tid = threadIdx.x;
  if (bid < 4){
    const int b = bid;
    const int lane = tid & 63;
    const float* base = pc + (size_t)b * 16384 * 3;
    float px[16], py[16], pz[16], dist[16];
    {
      union { float4 v4[12]; float f[48]; } u;
      const float4* src = (const float4*)(base + tid * 48);
#pragma unroll
      for (int q = 0; q < 12; ++q) u.v4[q] = src[q];
#pragma unroll
      for (int j = 0; j < 16; ++j){
        px[j] = u.f[j*3]; py[j] = u.f[j*3+1]; pz[j] = u.f[j*3+2];
        dist[j] = 1e10f;
      }
    }
    __shared__ unsigned long long keyslot[128];
    __shared__ float sbc[3];
    for (int i = tid; i < 128; i += 1024) keyslot[i] = 0ULL;
    __syncthreads();
    float cx = base[0], cy = base[1], cz = base[2];
    for (int t = 0; t < 128; ++t){
      if (tid == 0){
        centers[(b*128+t)*3+0] = cx;
        centers[(b*128+t)*3+1] = cy;
        centers[(b*128+t)*3+2] = cz;
      }
      if (t == 127) break;
      float bmax = -1.0f; int bidx = 0;
#pragma unroll
      for (int j = 0; j < 16; ++j){
        float dx = __fsub_rn(px[j], cx);
        float dy = __fsub_rn(py[j], cy);
        float dz = __fsub_rn(pz[j], cz);
        float d  = __fadd_rn(__fadd_rn(__fmul_rn(dx,dx), __fmul_rn(dy,dy)), __fmul_rn(dz,dz));
        float nd = fminf(dist[j], d);
        dist[j] = nd;
        if (nd > bmax){ bmax = nd; bidx = tid*16 + j; }
      }
      const float m = wmax_f32(bmax);
      const unsigned long long cand = __ballot(bmax == m);
      const int lowlane = __ffsll((long long)cand) - 1;
      const int widx = __shfl(bidx, lowlane, 64);
      if (lane == 0){
        const unsigned long long key = ((unsigned long long)__float_as_uint(m) << 32)
                                     | (unsigned long long)(0xFFFFFFFFu - (unsigned)widx);
        atomicMax(&keyslot[t], key);
      }
      __syncthreads();
      const unsigned long long gk = keyslot[t];
      const unsigned gidx = 0xFFFFFFFFu - (unsigned)(gk & 0xFFFFFFFFu);
      if ((unsigned)tid == (gidx >> 4)){
        const int jj = gidx & 15;
#pragma unroll
        for (int q2 = 0; q2 < 16; ++q2)
          if (q2 == jj){ sbc[0] = px[q2]; sbc[1] = py[q2]; sbc[2] = pz[q2]; }
      }
      __syncthreads();
      cx = sbc[0]; cy = sbc[1]; cz = sbc[2];
    }
  } else if (bid < 1028){
    __shared__ float ag[4096];
    for (int i = tid; i < 4096; i += 1024) ag[i] = agg[i];
    __syncthreads();
    const int wv = tid >> 6, lane = tid & 63;
    const int rbase = ((bid - 4)*16 + wv)*8;
    for (int rr = 0; rr < 8; ++rr){
      const int row = rbase + rr;
      const float* wp = spw + (size_t)row*1024 + lane*4;
      const float4 w0 = *(const float4*)(wp      );
      const float4 wq1 = *(const float4*)(wp + 256);
      const float4 wq2 = *(const float4*)(wp + 512);
      const float4 wq3 = *(const float4*)(wp + 768);
      float acc[4];
#pragma unroll
      for (int bb = 0; bb < 4; ++bb){
        const float* gp = &ag[bb*1024 + lane*4];
        const float4 g0 = *(const float4*)(gp      );
        const float4 g1 = *(const float4*)(gp + 256);
        const float4 g2 = *(const float4*)(gp + 512);
        const float4 g3 = *(const float4*)(gp + 768);
        acc[bb] = w0.x*g0.x + w0.y*g0.y + w0.z*g0.z + w0.w*g0.w
                + wq1.x*g1.x + wq1.y*g1.y + wq1.z*g1.z + wq1.w*g1.w
                + wq2.x*g2.x + wq2.y*g2.y + wq2.z*g2.z + wq2.w*g2.w
                + wq3.x*g3.x + wq3.y*g3.y + wq3.z*g3.z + wq3.w*g3.w;
      }
      float a0 = wredsum(acc[0]);
      float a1 = wredsum(acc[1]);
      float a2 = wredsum(acc[2]);
      float a3 = wredsum(acc[3]);
      if (lane == 0){
        const float bias = spb[row];
        x[(size_t)0*131072 + row] = a0 + bias;
        x[(size_t)1*131072 + row] = a1 + bias;
        x[(size_t)2*131072 + row] = a2 + bias;
        x[(size_t)3*131072 + row] = a3 + bias;
      }
    }
  } else {
    const size_t t = (size_t)(bid - 1028)*1024 + tid;   // 1572864 chunks (layer 0)
    const size_t i = t*8;
    const float* src;
    if (i < 3145728)       src = inw  + i;
    else if (i < 4194304)  src = outw + (i-3145728);
    else if (i < 8388608)  src = w1   + (i-4194304);
    else                   src = w2   + (i-8388608);
    float4 a = *(const float4*)src, bq = *(const float4*)(src+4);
    *(bf16x8_t*)(wbf + i) = pack8(a, bq);
  }
}

// ------------------------------------------------- mean over S (2-stage)
__global__ __launch_bounds__(256) void partial_kernel(const float* __restrict__ lh,
                                                      float* __restrict__ part){
  const int ph = blockIdx.x*256 + threadIdx.x;
  const int sc = blockIdx.y, b = blockIdx.z;
  const float* p = lh + ((size_t)b*512 + sc*64)*4096 + ph;
  float s0=0,s1=0,s2=0,s3=0;
  for (int j = 0; j < 64; j += 4){
    s0 += p[(size_t)(j+0)*4096];
    s1 += p[(size_t)(j+1)*4096];
    s2 += p[(size_t)(j+2)*4096];
    s3 += p[(size_t)(j+3)*4096];
  }
  part[(size_t)(b*8+sc)*4096 + ph] = (s0+s1)+(s2+s3);
}

__global__ __launch_bounds__(256) void combine_kernel(const float* __restrict__ part,
                                                      float* __restrict__ mlh){
  const int i = blockIdx.x*256 + threadIdx.x;
  const int b = i >> 12, ph = i & 4095;
  float s = 0;
#pragma unroll
  for (int sc = 0; sc < 8; ++sc) s += part[(size_t)(b*8+sc)*4096 + ph];
  mlh[i] = s * (1.0f/512.0f);
}

// ------------------------------------------------- agg = mean_lh @ fp_w.T + fp_b
__global__ __launch_bounds__(256) void agg_kernel(const float* __restrict__ mlh,
                                                  const float* __restrict__ fpw,
                                                  const float* __restrict__ fpb,
                                                  float* __restrict__ agg){
  const int o = blockIdx.x*4 + (threadIdx.x>>6);
  const int lane = threadIdx.x & 63;
  const int b = o >> 10, d = o & 1023;
  const float* mp = mlh + b*4096;
  const float* wp = fpw + (size_t)d*4096;
  float s = 0;
#pragma unroll 4
  for (int j = 0; j < 64; ++j){
    int ph = lane + j*64;
    s += mp[ph] * wp[ph];
  }
  s = wredsum(s);
  if (lane == 0) agg[o] = s + fpb[d];
}

// ------------------------------------------------- LayerNorm (layer-0 entry: x+pos), bf16 out
__global__ __launch_bounds__(256) void ln_kernel(const float* __restrict__ x,
                                                 const float* __restrict__ pos,
                                                 const float* __restrict__ w,
                                                 const float* __restrict__ bb,
                                                 __bf16* __restrict__ out){
  const int tok = blockIdx.x, g = tok & 127, t = threadIdx.x;
  const int lane = t & 63, wv = t >> 6;
  const float* xr = x + (size_t)tok*1024;
  float v[4];
#pragma unroll
  for (int j = 0; j < 4; ++j){
    int d = t + j*256;
    v[j] = xr[d] + pos[g*1024 + d];
  }
  __shared__ float r1[4], r2[4];
  float s = wredsum(v[0]+v[1]+v[2]+v[3]);
  if (lane == 0) r1[wv] = s;
  __syncthreads();
  const float mean = (r1[0]+r1[1]+r1[2]+r1[3]) * (1.0f/1024.0f);
  float sq = 0;
#pragma unroll
  for (int j = 0; j < 4; ++j){ float d0 = v[j]-mean; sq += d0*d0; }
  sq = wredsum(sq);
  if (lane == 0) r2[wv] = sq;
  __syncthreads();
  const float var = (r2[0]+r2[1]+r2[2]+r2[3]) * (1.0f/1024.0f);
  const float rs = rsqrtf(var + 1e-5f);
#pragma unroll
  for (int j = 0; j < 4; ++j){
    int d = t + j*256;
    out[(size_t)tok*1024 + d] = (__bf16)((v[j]-mean)*rs*w[d] + bb[d]);
  }
}

// ================== device bodies (transplanted from validated R16 kernels) ==================

// split-K GEMM 128x128 BK=64. smem: As 16KB @0, Ws 16KB @16384.
__device__ void dev_gemm_sk(char* sm, int bx, int by, int bz,
                            const __bf16* __restrict__ A, const __bf16* __restrict__ W,
                            float* __restrict__ parts, int M, int N, int K, int kc){
  __bf16* As = (__bf16*)sm;
  __bf16* Ws = (__bf16*)(sm + 16384);
  const int n0 = bx*128, m0 = by*128, z = bz;
  const int tid = threadIdx.x;
  const int lane = tid & 63, w = tid >> 6;
  const int wm = w >> 1, wn = w & 1;
  const int lr = lane & 15, g = lane >> 4;
  const int kbeg = z*kc;
  const int c0 = tid, c1 = tid+256, c2 = tid+512, c3 = tid+768;
  const int r0 = c0>>3, r1 = c1>>3, r2 = c2>>3, r3 = c3>>3;
  const int s0 = ((c0&7) ^ (r0&7))*8, s1 = ((c1&7) ^ (r1&7))*8;
  const int s2 = ((c2&7) ^ (r2&7))*8, s3 = ((c3&7) ^ (r3&7))*8;
  const __bf16* pa0 = A + (size_t)(m0+r0)*K + kbeg + s0;
  const __bf16* pa1 = A + (size_t)(m0+r1)*K + kbeg + s1;
  const __bf16* pa2 = A + (size_t)(m0+r2)*K + kbeg + s2;
  const __bf16* pa3 = A + (size_t)(m0+r3)*K + kbeg + s3;
  const __bf16* pw0 = W + (size_t)(n0+r0)*K + kbeg + s0;
  const __bf16* pw1 = W + (size_t)(n0+r1)*K + kbeg + s1;
  const __bf16* pw2 = W + (size_t)(n0+r2)*K + kbeg + s2;
  const __bf16* pw3 = W + (size_t)(n0+r3)*K + kbeg + s3;
  f32x4_t acc[4][4] = {};
  for (int k0 = 0; k0 < kc; k0 += 64){
    __syncthreads();
    gload16(pa0 + k0, &As[c0*8]);
    gload16(pa1 + k0, &As[c1*8]);
    gload16(pa2 + k0, &As[c2*8]);
    gload16(pa3 + k0, &As[c3*8]);
    gload16(pw0 + k0, &Ws[c0*8]);
    gload16(pw1 + k0, &Ws[c1*8]);
    gload16(pw2 + k0, &Ws[c2*8]);
    gload16(pw3 + k0, &Ws[c3*8]);
    __syncthreads();
#pragma unroll
    for (int ks2 = 0; ks2 < 2; ++ks2){
      bf16x8_t af[4], bf[4];
#pragma unroll
      for (int f = 0; f < 4; ++f){
        const int ra = wm*64 + f*16 + lr;
        const int rb = wn*64 + f*16 + lr;
        const int lq = ks2*4 + g;
        af[f] = *(bf16x8_t*)&As[ra*64 + (lq ^ (ra&7))*8];
        bf[f] = *(bf16x8_t*)&Ws[rb*64 + (lq ^ (rb&7))*8];
      }
#pragma unroll
      for (int i = 0; i < 4; ++i)
#pragma unroll
        for (int j = 0; j < 4; ++j)
          acc[i][j] = __builtin_amdgcn_mfma_f32_16x16x32_bf16(af[i], bf[j], acc[i][j], 0, 0, 0);
    }
  }
  float* C = parts + (size_t)z*M*N;
#pragma unroll
  for (int i = 0; i < 4; ++i)
#pragma unroll
    for (int j = 0; j < 4; ++j)
#pragma unroll
      for (int r = 0; r < 4; ++r){
        const int row = m0 + wm*64 + i*16 + g*4 + r;
        const int col = n0 + wn*64 + j*16 + lr;
        C[(size_t)row*N + col] = acc[i][j][r];
      }
}

// full-K GEMM 64x128 BK=64, fused epilogue. smem: As 8KB @0, Ws 16KB @8192.
template<int EPI>
__device__ void dev_gemm64f(char* sm, int bx, int by,
                            const __bf16* __restrict__ A, const __bf16* __restrict__ W,
                            const float* __restrict__ bias, __bf16* __restrict__ C,
                            int N, int K){
  __bf16* As = (__bf16*)sm;
  __bf16* Ws = (__bf16*)(sm + 8192);
  const int n0 = bx*128, m0 = by*64;
  const int tid = threadIdx.x;
  const int lane = tid & 63, w = tid >> 6;
  const int wm = w >> 1, wn = w & 1;
  const int lr = lane & 15, g = lane >> 4;
  const int cA0 = tid, cA1 = tid+256;
  const int rA0 = cA0>>3, rA1 = cA1>>3;
  const int sA0 = ((cA0&7)^(rA0&7))*8, sA1 = ((cA1&7)^(rA1&7))*8;
  const int cW0 = tid, cW1 = tid+256, cW2 = tid+512, cW3 = tid+768;
  const int rW0 = cW0>>3, rW1 = cW1>>3, rW2 = cW2>>3, rW3 = cW3>>3;
  const int sW0 = ((cW0&7)^(rW0&7))*8, sW1 = ((cW1&7)^(rW1&7))*8;
  const int sW2 = ((cW2&7)^(rW2&7))*8, sW3 = ((cW3&7)^(rW3&7))*8;
  const __bf16* pa0 = A + (size_t)(m0+rA0)*K + sA0;
  const __bf16* pa1 = A + (size_t)(m0+rA1)*K + sA1;
  const __bf16* pw0 = W + (size_t)(n0+rW0)*K + sW0;
  const __bf16* pw1 = W + (size_t)(n0+rW1)*K + sW1;
  const __bf16* pw2 = W + (size_t)(n0+rW2)*K + sW2;
  const __bf16* pw3 = W + (size_t)(n0+rW3)*K + sW3;
  f32x4_t acc[2][4] = {};
  for (int k0 = 0; k0 < K; k0 += 64){
    __syncthreads();
    gload16(pa0 + k0, &As[cA0*8]);
    gload16(pa1 + k0, &As[cA1*8]);
    gload16(pw0 + k0, &Ws[cW0*8]);
    gload16(pw1 + k0, &Ws[cW1*8]);
    gload16(pw2 + k0, &Ws[cW2*8]);
    gload16(pw3 + k0, &Ws[cW3*8]);
    __syncthreads();
#pragma unroll
    for (int ks2 = 0; ks2 < 2; ++ks2){
      bf16x8_t af[2], bf[4];
#pragma unroll
      for (int i = 0; i < 2; ++i){
        const int ra = wm*32 + i*16 + lr;
        const int lq = ks2*4 + g;
        af[i] = *(bf16x8_t*)&As[ra*64 + (lq ^ (ra&7))*8];
      }
#pragma unroll
      for (int j = 0; j < 4; ++j){
        const int rb = wn*64 + j*16 + lr;
        const int lq = ks2*4 + g;
        bf[j] = *(bf16x8_t*)&Ws[rb*64 + (lq ^ (rb&7))*8];
      }
#pragma unroll
      for (int i = 0; i < 2; ++i)
#pragma unroll
        for (int j = 0; j < 4; ++j)
          acc[i][j] = __builtin_amdgcn_mfma_f32_16x16x32_bf16(af[i], bf[j], acc[i][j], 0, 0, 0);
    }
  }
#pragma unroll
  for (int i = 0; i < 2; ++i)
#pragma unroll
    for (int j = 0; j < 4; ++j)
#pragma unroll
      for (int r = 0; r < 4; ++r){
        const int row = m0 + wm*32 + i*16 + g*4 + r;
        const int col = n0 + wn*64 + j*16 + lr;
        float v = acc[i][j][r] + bias[col];
        if (EPI == 2) v = v * 0.5f * (1.0f + erff(v * 0.70710678118654752440f));
        C[(size_t)row*N + col] = (__bf16)v;
      }
}

// fused attention (validated R6 body). smem: vt 32KB @0, pl 16KB @32768.
__device__ void dev_attn(char* sm, int vb,
                         const __bf16* __restrict__ qkv, __bf16* __restrict__ O){
  __bf16* vt = (__bf16*)sm;
  __bf16* pl = (__bf16*)(sm + 32768);
  const int bh = vb >> 1, half = vb & 1;
  const int b = bh>>3, h = bh&7;
  const int tid = threadIdx.x, w = tid>>6, lane = tid&63;
  const int lr = lane&15, g = lane>>4;
  __syncthreads();   // defensive: smem reused across stages
  {
    const int n = tid >> 1, kh = tid & 1;
    const __bf16* vbase = qkv + (size_t)(b*128)*3072 + 2048 + h*128 + n;
#pragma unroll
    for (int jb = 0; jb < 8; ++jb){
      bf16x8_t pk;
#pragma unroll
      for (int e = 0; e < 8; ++e) pk[e] = vbase[(size_t)(kh*64 + jb*8 + e)*3072];
      const int cb = kh*8 + jb;
      *(bf16x8_t*)&vt[n*128 + ((cb ^ (n&7)) * 8)] = pk;
    }
  }
  const __bf16* qbase = qkv + (size_t)(b*128)*3072 + h*128;
  const __bf16* kbase = qbase + 1024;
  const int qrow0 = half*64 + w*16;
  f32x4_t acc[8] = {};
#pragma unroll
  for (int ks = 0; ks < 4; ++ks){
    bf16x8_t aq, bk[8];
    aq = *(const bf16x8_t*)(qbase + (size_t)(qrow0 + lr)*3072 + ks*32 + g*8);
#pragma unroll
    for (int j = 0; j < 8; ++j)
      bk[j] = *(const bf16x8_t*)(kbase + (size_t)(j*16 + lr)*3072 + ks*32 + g*8);
#pragma unroll
    for (int j = 0; j < 8; ++j)
      acc[j] = __builtin_amdgcn_mfma_f32_16x16x32_bf16(aq, bk[j], acc[j], 0, 0, 0);
  }
  __syncthreads();
  const float scale = 0.088388347648318447f;  // 1/sqrt(128)
#pragma unroll
  for (int r = 0; r < 4; ++r){
    const int row = g*4 + r;
    float sv[8];
    float mx = -1e30f;
#pragma unroll
    for (int j = 0; j < 8; ++j){ sv[j] = acc[j][r]*scale; mx = fmaxf(mx, sv[j]); }
#pragma unroll
    for (int o = 1; o < 16; o <<= 1) mx = fmaxf(mx, __shfl_xor(mx, o, 64));
    float s = 0;
#pragma unroll
    for (int j = 0; j < 8; ++j){ sv[j] = expf(sv[j]-mx); s += sv[j]; }
#pragma unroll
    for (int o = 1; o < 16; o <<= 1) s += __shfl_xor(s, o, 64);
    const float inv = 1.0f/s;
#pragma unroll
    for (int j = 0; j < 8; ++j){
      const int col = j*16 + lr;
      const int slot = (col>>3) ^ (row&7);
      pl[w*2048 + row*128 + slot*8 + (lr&7)] = (__bf16)(sv[j]*inv);
    }
  }
  __syncthreads();
  f32x4_t acc2[8] = {};
#pragma unroll
  for (int ks = 0; ks < 4; ++ks){
    bf16x8_t ap, bv[8];
    {
      const int row = lr;
      const int slot = (ks*4 + g) ^ (row&7);
      ap = *(bf16x8_t*)&pl[w*2048 + row*128 + slot*8];
    }
#pragma unroll
    for (int j = 0; j < 8; ++j){
      const int rowv = j*16 + lr;
      const int cb = ks*4 + g;
      bv[j] = *(bf16x8_t*)&vt[rowv*128 + ((cb ^ (rowv&7))*8)];
    }
#pragma unroll
    for (int j = 0; j < 8; ++j)
      acc2[j] = __builtin_amdgcn_mfma_f32_16x16x32_bf16(ap, bv[j], acc2[j], 0, 0, 0);
  }
#pragma unroll
  for (int j = 0; j < 8; ++j)
#pragma unroll
    for (int r = 0; r < 4; ++r){
      const int row = qrow0 + g*4 + r;
      const int col = j*16 + lr;
      O[(size_t)(b*128+row)*1024 + h*128 + col] = (__bf16)acc2[j][r];
    }
}

// residual combine + optional LN (R16 body, NSPLIT=8 unrolled). smem: r1/r2 @0.
template<int MODE>
__device__ void dev_comb_res_ln(char* sm, int tok,
                                const float* __restrict__ parts,
                                const float* __restrict__ bias,
                                const float* __restrict__ pos,
                                const float* __restrict__ lw,
                                const float* __restrict__ lb,
                                float* __restrict__ x, __bf16* __restrict__ xn){
  float* r1 = (float*)sm;
  float* r2 = r1 + 4;
  const int gi = tok & 127, t = threadIdx.x;
  const int lane = t & 63, wv = t >> 6;
  __syncthreads();   // defensive: smem reuse across consecutive calls
  float v[4];
#pragma unroll
  for (int j = 0; j < 4; ++j){
    const int d = t + j*256;
    const size_t idx = (size_t)tok*1024 + d;
    float s = 0;
#pragma unroll
    for (int z = 0; z < 8; ++z) s += parts[(size_t)z*524288 + idx];
    float val = x[idx] + s + bias[d];
    x[idx] = val;
    v[j] = val;
  }
  if (MODE == 2){
#pragma unroll
    for (int j = 0; j < 4; ++j){
      const int d = t + j*256;
      xn[(size_t)tok*1024 + d] = (__bf16)v[j];
    }
    return;
  }
  float u[4];
#pragma unroll
  for (int j = 0; j < 4; ++j){
    const int d = t + j*256;
    u[j] = v[j] + (MODE == 1 ? pos[gi*1024 + d] : 0.0f);
  }
  float s1 = wredsum(u[0]+u[1]+u[2]+u[3]);
  if (lane == 0) r1[wv] = s1;
  __syncthreads();
  const float mean = (r1[0]+r1[1]+r1[2]+r1[3]) * (1.0f/1024.0f);
  float sq = 0;
#pragma unroll
  for (int j = 0; j < 4; ++j){ float d0 = u[j]-mean; sq += d0*d0; }
  sq = wredsum(sq);
  if (lane == 0) r2[wv] = sq;
  __syncthreads();
  const float var = (r2[0]+r2[1]+r2[2]+r2[3]) * (1.0f/1024.0f);
  const float rs = rsqrtf(var + 1e-5f);
#pragma unroll
  for (int j = 0; j < 4; ++j){
    const int d = t + j*256;
    xn[(size_t)tok*1024 + d] = (__bf16)((u[j]-mean)*rs*lw[d] + lb[d]);
  }
}

// head: c1 combine + BN + ReLU + c2 GEMV + centers (R13 body). smem: hrow 4KB @0.
__device__ void dev_head(char* sm, int tok,
                         const float* __restrict__ parts, const float* __restrict__ c1b,
                         const float* __restrict__ bnm, const float* __restrict__ bnv,
                         const float* __restrict__ bng, const float* __restrict__ bnb,
                         const float* __restrict__ c2w, const float* __restrict__ c2b,
                         const float* __restrict__ centers, float* __restrict__ out){
  float* hrow = (float*)sm;
  const int t = threadIdx.x;
  const int wv = t >> 6, lane = t & 63;
  __syncthreads();   // fix R15 latent bug: protect hrow across consecutive calls
#pragma unroll
  for (int j = 0; j < 4; ++j){
    const int d = t + j*256;
    const size_t idx = (size_t)tok*1024 + d;
    float s = 0;
#pragma unroll
    for (int z = 0; z < 8; ++z) s += parts[(size_t)z*524288 + idx];
    float v = s + c1b[d];
    v = (v - bnm[d]) * rsqrtf(bnv[d] + 1e-5f) * bng[d] + bnb[d];
    hrow[d] = fmaxf(v, 0.0f);
  }
  __syncthreads();
  for (int i = 0; i < 24; ++i){
    const int n = wv*24 + i;
    const float* wp = c2w + (size_t)n*1024;
    float s = 0;
#pragma unroll 4
    for (int j = 0; j < 16; ++j){
      const int k = lane + j*64;
      s += hrow[k] * wp[k];
    }
    s = wredsum(s);
    if (lane == 0) out[(size_t)tok*96 + n] = s + c2b[n] + centers[tok*3 + (n % 3)];
  }
}

// weight fp32->bf16 conversion of `cnt` chunks at cbase + k*cstride (layer ll)
__device__ void dev_conv_layer(int ll, int cbase, int cstride, int cnt,
                               const float* inw, const float* outw,
                               const float* w1, const float* w2,
                               __bf16* wbf){
  for (int k = 0; k < cnt; ++k){
    const size_t c = (size_t)cbase + (size_t)k*cstride;
    const size_t i = c*8;
    const float* src;
    if (i < 3145728)       src = inw  + (size_t)ll*3145728 + i;
    else if (i < 4194304)  src = outw + (size_t)ll*1048576 + (i-3145728);
    else if (i < 8388608)  src = w1   + (size_t)ll*4194304 + (i-4194304);
    else                   src = w2   + (size_t)ll*4194304 + (i-8388608);
    float4 a = *(const float4*)src, bq = *(const float4*)(src+4);
    *(bf16x8_t*)(wbf + (size_t)ll*12582912 + i) = pack8(a, bq);
  }
}

// ---------------- manual grid barrier (256 blocks, device-scope atomics) ----------------
__device__ __forceinline__ void gridbar(unsigned* cnt, unsigned* gen){
  __syncthreads();
  if (threadIdx.x == 0){
    __threadfence();                               // release prior writes
    const unsigned g = atomicAdd(gen, 0u);         // read generation
    const unsigned arr = atomicAdd(cnt, 1u);
    if (arr == 255u){
      atomicExch(cnt, 0u);
      atomicAdd(gen, 1u);
    } else {
      while (atomicAdd(gen, 0u) == g){ __builtin_amdgcn_s_sleep(8); }
    }
    __threadfence();                               // acquire
  }
  __syncthreads();
}

// ================== mega kernel: full transformer + head, regular launch ==================
struct MP {
  const float *inw, *outw, *w1, *w2, *c1w;
  const float *inb, *outb, *ln2w, *ln2b, *b1, *b2, *pos, *ln1w, *ln1b;
  const float *c1b, *bnm, *bnv, *bng, *bnb, *c2w, *c2b, *cent;
  float *parts, *x, *out;
  __bf16 *wbf, *xn, *qkv, *obuf, *hbf, *xbf;
  unsigned *bcnt, *bgen;
};

__global__ __launch_bounds__(256, 1) void mega(MP p){
  __shared__ __align__(16) char smem[49152];
  const int bid = blockIdx.x;
  const int tid = threadIdx.x;
  for (int l = 0; l < 4; ++l){
    const __bf16* wl = p.wbf + (size_t)l*12582912;
    // S1: qkv (192 tiles); 64 idle blocks convert next weights (or c1 at l==3)
    if (bid < 192){
      dev_gemm64f<0>(smem, bid % 24, bid / 24, p.xn, wl, p.inb + l*3072, p.qkv, 3072, 1024);
    } else {
      const int th = (bid-192)*256 + tid;          // 0..16383
      if (l < 3) dev_conv_layer(l+1, th, 16384, 24, p.inw, p.outw, p.w1, p.w2, p.wbf);
      else {
        for (int k = 0; k < 8; ++k){               // c1: 131072 chunks
          const size_t i = ((size_t)th + (size_t)k*16384)*8;
          float4 a = *(const float4*)(p.c1w + i), bq = *(const float4*)(p.c1w + i + 4);
          *(bf16x8_t*)(p.wbf + 50331648 + i) = pack8(a, bq);
        }
      }
    }
    gridbar(p.bcnt, p.bgen);
    // S2: attn (64 blocks); 192 idle blocks finish next-layer conversion
    if (bid < 64){
      dev_attn(smem, bid, p.qkv, p.obuf);
    } else if (l < 3){
      const int th = (bid-64)*256 + tid;           // 0..49151
      dev_conv_layer(l+1, 393216 + th, 49152, 24, p.inw, p.outw, p.w1, p.w2, p.wbf);
    }
    gridbar(p.bcnt, p.bgen);
    // S3: attn-out split-8 (8,4,8)=256 tiles
    dev_gemm_sk(smem, bid & 7, (bid >> 3) & 3, bid >> 5,
                p.obuf, wl + 3145728, p.parts, 512, 1024, 1024, 128);
    gridbar(p.bcnt, p.bgen);
    // S4: residual + LN2 (2 tokens/block)
    dev_comb_res_ln<0>(smem, 2*bid,   p.parts, p.outb + l*1024, nullptr,
                       p.ln2w + l*1024, p.ln2b + l*1024, p.x, p.xn);
    dev_comb_res_ln<0>(smem, 2*bid+1, p.parts, p.outb + l*1024, nullptr,
                       p.ln2w + l*1024, p.ln2b + l*1024, p.x, p.xn);
    gridbar(p.bcnt, p.bgen);
    // S5: mlp1 full-K (32,8)=256 tiles, GELU fused
    dev_gemm64f<2>(smem, bid & 31, bid >> 5, p.xn, wl + 4194304, p.b1 + l*4096,
                   p.hbf, 4096, 1024);
    gridbar(p.bcnt, p.bgen);
    // S6: mlp2 split-8 (8,4,8)=256 tiles
    dev_gemm_sk(smem, bid & 7, (bid >> 3) & 3, bid >> 5,
                p.hbf, wl + 8388608, p.parts, 512, 1024, 4096, 512);
    gridbar(p.bcnt, p.bgen);
    // S7: residual + (pos+LN1[l+1]) or final bf16 copy
    if (l < 3){
      dev_comb_res_ln<1>(smem, 2*bid,   p.parts, p.b2 + l*1024, p.pos,
                         p.ln1w + (l+1)*1024, p.ln1b + (l+1)*1024, p.x, p.xn);
      dev_comb_res_ln<1>(smem, 2*bid+1, p.parts, p.b2 + l*1024, p.pos,
                         p.ln1w + (l+1)*1024, p.ln1b + (l+1)*1024, p.x, p.xn);
    } else {
      dev_comb_res_ln<2>(smem, 2*bid,   p.parts, p.b2 + l*1024, nullptr,
                         nullptr, nullptr, p.x, p.xbf);
      dev_comb_res_ln<2>(smem, 2*bid+1, p.parts, p.b2 + l*1024, nullptr,
                         nullptr, nullptr, p.x, p.xbf);
    }
    gridbar(p.bcnt, p.bgen);
  }
  // c1 split-8 (8,4,8)=256 tiles
  dev_gemm_sk(smem, bid & 7, (bid >> 3) & 3, bid >> 5,
              p.xbf, p.wbf + 50331648, p.parts, 512, 1024, 1024, 128);
  gridbar(p.bcnt, p.bgen);
  // head (2 tokens/block)
  dev_head(smem, 2*bid,   p.parts, p.c1b, p.bnm, p.bnv, p.bng, p.bnb, p.c2w, p.c2b, p.cent, p.out);
  dev_head(smem, 2*bid+1, p.parts, p.c1b, p.bnm, p.bnv, p.bng, p.bnb, p.c2w, p.c2b, p.cent, p.out);
}

// =================================================================
extern "C" void kernel_launch(void* const* d_in, const int* in_sizes, int n_in,
                              void* d_out, int out_size, void* d_ws, size_t ws_size,
                              hipStream_t stream){
  const float* lh   = (const float*)d_in[0];
  const float* pc   = (const float*)d_in[1];
  const float* fpw  = (const float*)d_in[2];
  const float* fpb  = (const float*)d_in[3];
  const float* spw  = (const float*)d_in[4];
  const float* spb  = (const float*)d_in[5];
  const float* pos  = (const float*)d_in[6];
  const float* ln1w = (const float*)d_in[7];
  const float* ln1b = (const float*)d_in[8];
  const float* inw  = (const float*)d_in[9];
  const float* inb  = (const float*)d_in[10];
  const float* outw = (const float*)d_in[11];
  const float* outb = (const float*)d_in[12];
  const float* ln2w = (const float*)d_in[13];
  const float* ln2b = (const float*)d_in[14];
  const float* w1   = (const float*)d_in[15];
  const float* b1   = (const float*)d_in[16];
  const float* w2   = (const float*)d_in[17];
  const float* b2   = (const float*)d_in[18];
  const float* c1w  = (const float*)d_in[19];
  const float* c1b  = (const float*)d_in[20];
  const float* bng  = (const float*)d_in[21];
  const float* bnbt = (const float*)d_in[22];
  const float* bnm  = (const float*)d_in[23];
  const float* bnv  = (const float*)d_in[24];
  const float* c2w  = (const float*)d_in[25];
  const float* c2b  = (const float*)d_in[26];
  float* out = (float*)d_out;

  // ---- workspace layout ----
  float* f = (float*)d_ws;
  float* parts = f;              f += 16*524288;  // split-K fp32 partials (32 MB)
  float* part  = f;              f += 131072;
  float* mlh   = f;              f += 16384;
  float* agg   = f;              f += 4096;
  float* x     = f;              f += 524288;     // residual stream fp32
  float* cent  = f;              f += 2048;       // centers (+pad)
  unsigned* bar = (unsigned*)f;  f += 16;         // grid barrier state (cnt, gen)
  __bf16* bfp = (__bf16*)f;
  __bf16* xn   = bfp;            bfp += 524288;
  __bf16* qkv  = bfp;            bfp += 1572864;
  __bf16* obuf = bfp;            bfp += 524288;
  __bf16* hbf  = bfp;            bfp += 2097152;
  __bf16* xbf  = bfp;            bfp += 524288;
  __bf16* wbf  = bfp;            bfp += 51380224;

  hipMemsetAsync(bar, 0, 2*sizeof(unsigned), stream);
  partial_kernel<<<dim3(16,8,4), 256, 0, stream>>>(lh, part);
  combine_kernel<<<64, 256, 0, stream>>>(part, mlh);
  agg_kernel<<<1024, 256, 0, stream>>>(mlh, fpw, fpb, agg);
  fused_front<<<2564, 1024, 0, stream>>>(pc, cent, agg, spw, spb, x,
                                         inw, outw, w1, w2, wbf);
  ln_kernel<<<512, 256, 0, stream>>>(x, pos, ln1w, ln1b, xn);

  MP mp;
  mp.inw = inw; mp.outw = outw; mp.w1 = w1; mp.w2 = w2; mp.c1w = c1w;
  mp.inb = inb; mp.outb = outb; mp.ln2w = ln2w; mp.ln2b = ln2b;
  mp.b1 = b1; mp.b2 = b2; mp.pos = pos; mp.ln1w = ln1w; mp.ln1b = ln1b;
  mp.c1b = c1b; mp.bnm = bnm; mp.bnv = bnv; mp.bng = bng; mp.bnb = bnbt;
  mp.c2w = c2w; mp.c2b = c2b; mp.cent = cent;
  mp.parts = parts; mp.x = x; mp.out = out;
  mp.wbf = wbf; mp.xn = xn; mp.qkv = qkv; mp.obuf = obuf; mp.hbf = hbf; mp.xbf = xbf;
  mp.bcnt = bar; mp.bgen = bar + 1;

  mega<<<256, 256, 0, stream>>>(mp);
}

// Round 18
// 679.123 us; speedup vs baseline: 2.5717x; 2.5717x over previous
//
#include <hip/hip_runtime.h>
#include <hip/hip_bf16.h>
#include <math.h>

// Shapes (fixed): B=4, S=512, PH=4096, N=16384, D=1024, G=128, H=8, L=4, FF=4096, GS=32, HD=128

typedef __bf16 bf16x8_t __attribute__((ext_vector_type(8)));
typedef float  f32x4_t  __attribute__((ext_vector_type(4)));

__device__ __forceinline__ float wredsum(float v){
#pragma unroll
  for (int o = 32; o; o >>= 1) v += __shfl_down(v, o, 64);
  return v;  // valid in lane 0
}

__device__ __forceinline__ bf16x8_t pack8(float4 a, float4 b){
  bf16x8_t v;
  v[0]=(__bf16)a.x; v[1]=(__bf16)a.y; v[2]=(__bf16)a.z; v[3]=(__bf16)a.w;
  v[4]=(__bf16)b.x; v[5]=(__bf16)b.y; v[6]=(__bf16)b.z; v[7]=(__bf16)b.w;
  return v;
}

__device__ __forceinline__ void gload16(const void* g, void* l){
  __builtin_amdgcn_global_load_lds((const __attribute__((address_space(1))) unsigned int*)g,
                                   (__attribute__((address_space(3))) unsigned int*)l, 16, 0, 0);
}

// f32 wave-max via ds_swizzle xor stages (32-lane halves) + cross-half shfl (validated R14)
__device__ __forceinline__ float wmax_f32(float m){
  m = fmaxf(m, __int_as_float(__builtin_amdgcn_ds_swizzle(__float_as_int(m), 0x041F)));
  m = fmaxf(m, __int_as_float(__builtin_amdgcn_ds_swizzle(__float_as_int(m), 0x081F)));
  m = fmaxf(m, __int_as_float(__builtin_amdgcn_ds_swizzle(__float_as_int(m), 0x101F)));
  m = fmaxf(m, __int_as_float(__builtin_amdgcn_ds_swizzle(__float_as_int(m), 0x201F)));
  m = fmaxf(m, __int_as_float(__builtin_amdgcn_ds_swizzle(__float_as_int(m), 0x401F)));
  m = fmaxf(m, __shfl_xor(m, 32, 64));
  return m;  // valid in all lanes
}

// ---------------------------------------------------------------- fused front-end
// blocks 0..3: FPS v4; 4..1027: sp GEMV (537 MB); 1028..2563: LAYER-0 weight fp32->bf16
__global__ __launch_bounds__(1024) void fused_front(
  const float* __restrict__ pc, float* __restrict__ centers,
  const float* __restrict__ agg, const float* __restrict__ spw,
  const float* __restrict__ spb, float* __restrict__ x,
  const float* __restrict__ inw, const float* __restrict__ outw,
  const float* __restrict__ w1, const float* __restrict__ w2,
  __bf16* __restrict__ wbf)
{
  const int bid = blockIdx.x;
  const int tid = threadIdx.x;
  if (bid < 4){
    // ---------------- FPS v4 (validated R14) ----------------
    const int b = bid;
    const int lane = tid & 63;
    const float* base = pc + (size_t)b * 16384 * 3;
    float px[16], py[16], pz[16], dist[16];
    {
      union { float4 v4[12]; float f[48]; } u;
      const float4* src = (const float4*)(base + tid * 48);
#pragma unroll
      for (int q = 0; q < 12; ++q) u.v4[q] = src[q];
#pragma unroll
      for (int j = 0; j < 16; ++j){
        px[j] = u.f[j*3]; py[j] = u.f[j*3+1]; pz[j] = u.f[j*3+2];
        dist[j] = 1e10f;
      }
    }
    __shared__ unsigned long long keyslot[128];
    __shared__ float sbc[3];
    for (int i = tid; i < 128; i += 1024) keyslot[i] = 0ULL;
    __syncthreads();
    float cx = base[0], cy = base[1], cz = base[2];
    for (int t = 0; t < 128; ++t){
      if (tid == 0){
        centers[(b*128+t)*3+0] = cx;
        centers[(b*128+t)*3+1] = cy;
        centers[(b*128+t)*3+2] = cz;
      }
      if (t == 127) break;
      float bmax = -1.0f; int bidx = 0;
#pragma unroll
      for (int j = 0; j < 16; ++j){
        float dx = __fsub_rn(px[j], cx);
        float dy = __fsub_rn(py[j], cy);
        float dz = __fsub_rn(pz[j], cz);
        float d  = __fadd_rn(__fadd_rn(__fmul_rn(dx,dx), __fmul_rn(dy,dy)), __fmul_rn(dz,dz));
        float nd = fminf(dist[j], d);
        dist[j] = nd;
        if (nd > bmax){ bmax = nd; bidx = tid*16 + j; }
      }
      const float m = wmax_f32(bmax);
      const unsigned long long cand = __ballot(bmax == m);
      const int lowlane = __ffsll((long long)cand) - 1;
      const int widx = __shfl(bidx, lowlane, 64);
      if (lane == 0){
        const unsigned long long key = ((unsigned long long)__float_as_uint(m) << 32)
                                     | (unsigned long long)(0xFFFFFFFFu - (unsigned)widx);
        atomicMax(&keyslot[t], key);
      }
      __syncthreads();
      const unsigned long long gk = keyslot[t];
      const unsigned gidx = 0xFFFFFFFFu - (unsigned)(gk & 0xFFFFFFFFu);
      if ((unsigned)tid == (gidx >> 4)){
        const int jj = gidx & 15;
#pragma unroll
        for (int q2 = 0; q2 < 16; ++q2)
          if (q2 == jj){ sbc[0] = px[q2]; sbc[1] = py[q2]; sbc[2] = pz[q2]; }
      }
      __syncthreads();
      cx = sbc[0]; cy = sbc[1]; cz = sbc[2];
    }
  } else if (bid < 1028){
    // ---------------- sp: x0 = agg @ sp_w.T + sp_b ----------------
    __shared__ float ag[4096];
    for (int i = tid; i < 4096; i += 1024) ag[i] = agg[i];
    __syncthreads();
    const int wv = tid >> 6, lane = tid & 63;
    const int rbase = ((bid - 4)*16 + wv)*8;
    for (int rr = 0; rr < 8; ++rr){
      const int row = rbase + rr;
      const float* wp = spw + (size_t)row*1024 + lane*4;
      const float4 w0 = *(const float4*)(wp      );
      const float4 wq1 = *(const float4*)(wp + 256);
      const float4 wq2 = *(const float4*)(wp + 512);
      const float4 wq3 = *(const float4*)(wp + 768);
      float acc[4];
#pragma unroll
      for (int bb = 0; bb < 4; ++bb){
        const float* gp = &ag[bb*1024 + lane*4];
        const float4 g0 = *(const float4*)(gp      );
        const float4 g1 = *(const float4*)(gp + 256);
        const float4 g2 = *(const float4*)(gp + 512);
        const float4 g3 = *(const float4*)(gp + 768);
        acc[bb] = w0.x*g0.x + w0.y*g0.y + w0.z*g0.z + w0.w*g0.w
                + wq1.x*g1.x + wq1.y*g1.y + wq1.z*g1.z + wq1.w*g1.w
                + wq2.x*g2.x + wq2.y*g2.y + wq2.z*g2.z + wq2.w*g2.w
                + wq3.x*g3.x + wq3.y*g3.y + wq3.z*g3.z + wq3.w*g3.w;
      }
      float a0 = wredsum(acc[0]);
      float a1 = wredsum(acc[1]);
      float a2 = wredsum(acc[2]);
      float a3 = wredsum(acc[3]);
      if (lane == 0){
        const float bias = spb[row];
        x[(size_t)0*131072 + row] = a0 + bias;
        x[(size_t)1*131072 + row] = a1 + bias;
        x[(size_t)2*131072 + row] = a2 + bias;
        x[(size_t)3*131072 + row] = a3 + bias;
      }
    }
  } else {
    // ---------------- weight fp32 -> bf16, LAYER 0 only ----------------
    const size_t t = (size_t)(bid - 1028)*1024 + tid;   // 1572864 chunks
    const size_t i = t*8;
    const float* src;
    if (i < 3145728)       src = inw  + i;
    else if (i < 4194304)  src = outw + (i-3145728);
    else if (i < 8388608)  src = w1   + (i-4194304);
    else                   src = w2   + (i-8388608);
    float4 a = *(const float4*)src, bq = *(const float4*)(src+4);
    *(bf16x8_t*)(wbf + i) = pack8(a, bq);
  }
}

// ------------------------------------------------- mean over S (2-stage)
__global__ __launch_bounds__(256) void partial_kernel(const float* __restrict__ lh,
                                                      float* __restrict__ part){
  const int ph = blockIdx.x*256 + threadIdx.x;
  const int sc = blockIdx.y, b = blockIdx.z;
  const float* p = lh + ((size_t)b*512 + sc*64)*4096 + ph;
  float s0=0,s1=0,s2=0,s3=0;
  for (int j = 0; j < 64; j += 4){
    s0 += p[(size_t)(j+0)*4096];
    s1 += p[(size_t)(j+1)*4096];
    s2 += p[(size_t)(j+2)*4096];
    s3 += p[(size_t)(j+3)*4096];
  }
  part[(size_t)(b*8+sc)*4096 + ph] = (s0+s1)+(s2+s3);
}

__global__ __launch_bounds__(256) void combine_kernel(const float* __restrict__ part,
                                                      float* __restrict__ mlh){
  const int i = blockIdx.x*256 + threadIdx.x;
  const int b = i >> 12, ph = i & 4095;
  float s = 0;
#pragma unroll
  for (int sc = 0; sc < 8; ++sc) s += part[(size_t)(b*8+sc)*4096 + ph];
  mlh[i] = s * (1.0f/512.0f);
}

// ------------------------------------------------- agg = mean_lh @ fp_w.T + fp_b
__global__ __launch_bounds__(256) void agg_kernel(const float* __restrict__ mlh,
                                                  const float* __restrict__ fpw,
                                                  const float* __restrict__ fpb,
                                                  float* __restrict__ agg){
  const int o = blockIdx.x*4 + (threadIdx.x>>6);
  const int lane = threadIdx.x & 63;
  const int b = o >> 10, d = o & 1023;
  const float* mp = mlh + b*4096;
  const float* wp = fpw + (size_t)d*4096;
  float s = 0;
#pragma unroll 4
  for (int j = 0; j < 64; ++j){
    int ph = lane + j*64;
    s += mp[ph] * wp[ph];
  }
  s = wredsum(s);
  if (lane == 0) agg[o] = s + fpb[d];
}

// ------------------------------------------------- LayerNorm (optional +pos), bf16 out
__global__ __launch_bounds__(256) void ln_kernel(const float* __restrict__ x,
                                                 const float* __restrict__ pos,
                                                 const float* __restrict__ w,
                                                 const float* __restrict__ bb,
                                                 __bf16* __restrict__ out){
  const int tok = blockIdx.x, g = tok & 127, t = threadIdx.x;
  const int lane = t & 63, wv = t >> 6;
  const float* xr = x + (size_t)tok*1024;
  float v[4];
#pragma unroll
  for (int j = 0; j < 4; ++j){
    int d = t + j*256;
    float val = xr[d];
    if (pos) val += pos[g*1024 + d];
    v[j] = val;
  }
  __shared__ float r1[4], r2[4];
  float s = wredsum(v[0]+v[1]+v[2]+v[3]);
  if (lane == 0) r1[wv] = s;
  __syncthreads();
  const float mean = (r1[0]+r1[1]+r1[2]+r1[3]) * (1.0f/1024.0f);
  float sq = 0;
#pragma unroll
  for (int j = 0; j < 4; ++j){ float d0 = v[j]-mean; sq += d0*d0; }
  sq = wredsum(sq);
  if (lane == 0) r2[wv] = sq;
  __syncthreads();
  const float var = (r2[0]+r2[1]+r2[2]+r2[3]) * (1.0f/1024.0f);
  const float rs = rsqrtf(var + 1e-5f);
#pragma unroll
  for (int j = 0; j < 4; ++j){
    int d = t + j*256;
    out[(size_t)tok*1024 + d] = (__bf16)((v[j]-mean)*rs*w[d] + bb[d]);
  }
}

// ------------------------------------------------- bf16 MFMA split-K GEMM, 128x128 tile, BK=64
// (validated R10 body: single-buffer 2-barrier, XOR quarter-swizzle w/ pre-swizzled source)
__global__ __launch_bounds__(256) void gemm_sk(
  const __bf16* __restrict__ A, const __bf16* __restrict__ W,
  float* __restrict__ parts, int M, int N, int K, int kc)
{
  __shared__ __bf16 As[128*64];
  __shared__ __bf16 Ws[128*64];
  const int n0 = blockIdx.x*128, m0 = blockIdx.y*128, z = blockIdx.z;
  const int tid = threadIdx.x;
  const int lane = tid & 63, w = tid >> 6;
  const int wm = w >> 1, wn = w & 1;
  const int lr = lane & 15, g = lane >> 4;
  const int kbeg = z*kc;
  const int c0 = tid, c1 = tid+256, c2 = tid+512, c3 = tid+768;
  const int r0 = c0>>3, r1 = c1>>3, r2 = c2>>3, r3 = c3>>3;
  const int s0 = ((c0&7) ^ (r0&7))*8, s1 = ((c1&7) ^ (r1&7))*8;
  const int s2 = ((c2&7) ^ (r2&7))*8, s3 = ((c3&7) ^ (r3&7))*8;
  const __bf16* pa0 = A + (size_t)(m0+r0)*K + kbeg + s0;
  const __bf16* pa1 = A + (size_t)(m0+r1)*K + kbeg + s1;
  const __bf16* pa2 = A + (size_t)(m0+r2)*K + kbeg + s2;
  const __bf16* pa3 = A + (size_t)(m0+r3)*K + kbeg + s3;
  const __bf16* pw0 = W + (size_t)(n0+r0)*K + kbeg + s0;
  const __bf16* pw1 = W + (size_t)(n0+r1)*K + kbeg + s1;
  const __bf16* pw2 = W + (size_t)(n0+r2)*K + kbeg + s2;
  const __bf16* pw3 = W + (size_t)(n0+r3)*K + kbeg + s3;
  f32x4_t acc[4][4] = {};
  for (int k0 = 0; k0 < kc; k0 += 64){
    __syncthreads();
    gload16(pa0 + k0, &As[c0*8]);
    gload16(pa1 + k0, &As[c1*8]);
    gload16(pa2 + k0, &As[c2*8]);
    gload16(pa3 + k0, &As[c3*8]);
    gload16(pw0 + k0, &Ws[c0*8]);
    gload16(pw1 + k0, &Ws[c1*8]);
    gload16(pw2 + k0, &Ws[c2*8]);
    gload16(pw3 + k0, &Ws[c3*8]);
    __syncthreads();
#pragma unroll
    for (int ks2 = 0; ks2 < 2; ++ks2){
      bf16x8_t af[4], bf[4];
#pragma unroll
      for (int f = 0; f < 4; ++f){
        const int ra = wm*64 + f*16 + lr;
        const int rb = wn*64 + f*16 + lr;
        const int lq = ks2*4 + g;
        af[f] = *(bf16x8_t*)&As[ra*64 + (lq ^ (ra&7))*8];
        bf[f] = *(bf16x8_t*)&Ws[rb*64 + (lq ^ (rb&7))*8];
      }
#pragma unroll
      for (int i = 0; i < 4; ++i)
#pragma unroll
        for (int j = 0; j < 4; ++j)
          acc[i][j] = __builtin_amdgcn_mfma_f32_16x16x32_bf16(af[i], bf[j], acc[i][j], 0, 0, 0);
    }
  }
  float* C = parts + (size_t)z*M*N;
#pragma unroll
  for (int i = 0; i < 4; ++i)
#pragma unroll
    for (int j = 0; j < 4; ++j)
#pragma unroll
      for (int r = 0; r < 4; ++r){
        const int row = m0 + wm*64 + i*16 + g*4 + r;
        const int col = n0 + wn*64 + j*16 + lr;
        C[(size_t)row*N + col] = acc[i][j][r];
      }
}

// ------------------------------------------------- bf16 MFMA full-K GEMM, 64x128 tile, BK=64
// Direct bf16 output with fused epilogue (validated R13).
// EPI: 0 = bias -> bf16;  2 = bias + exact GELU -> bf16.
template<int EPI>
__global__ __launch_bounds__(256) void gemm64f(
  const __bf16* __restrict__ A, const __bf16* __restrict__ W,
  const float* __restrict__ bias, __bf16* __restrict__ C,
  int M, int N, int K)
{
  __shared__ __bf16 As[64*64];     // 8 KB
  __shared__ __bf16 Ws[128*64];    // 16 KB
  const int n0 = blockIdx.x*128, m0 = blockIdx.y*64;
  const int tid = threadIdx.x;
  const int lane = tid & 63, w = tid >> 6;
  const int wm = w >> 1, wn = w & 1;
  const int lr = lane & 15, g = lane >> 4;
  const int cA0 = tid, cA1 = tid+256;
  const int rA0 = cA0>>3, rA1 = cA1>>3;
  const int sA0 = ((cA0&7)^(rA0&7))*8, sA1 = ((cA1&7)^(rA1&7))*8;
  const int cW0 = tid, cW1 = tid+256, cW2 = tid+512, cW3 = tid+768;
  const int rW0 = cW0>>3, rW1 = cW1>>3, rW2 = cW2>>3, rW3 = cW3>>3;
  const int sW0 = ((cW0&7)^(rW0&7))*8, sW1 = ((cW1&7)^(rW1&7))*8;
  const int sW2 = ((cW2&7)^(rW2&7))*8, sW3 = ((cW3&7)^(rW3&7))*8;
  const __bf16* pa0 = A + (size_t)(m0+rA0)*K + sA0;
  const __bf16* pa1 = A + (size_t)(m0+rA1)*K + sA1;
  const __bf16* pw0 = W + (size_t)(n0+rW0)*K + sW0;
  const __bf16* pw1 = W + (size_t)(n0+rW1)*K + sW1;
  const __bf16* pw2 = W + (size_t)(n0+rW2)*K + sW2;
  const __bf16* pw3 = W + (size_t)(n0+rW3)*K + sW3;
  f32x4_t acc[2][4] = {};
  for (int k0 = 0; k0 < K; k0 += 64){
    __syncthreads();
    gload16(pa0 + k0, &As[cA0*8]);
    gload16(pa1 + k0, &As[cA1*8]);
    gload16(pw0 + k0, &Ws[cW0*8]);
    gload16(pw1 + k0, &Ws[cW1*8]);
    gload16(pw2 + k0, &Ws[cW2*8]);
    gload16(pw3 + k0, &Ws[cW3*8]);
    __syncthreads();
#pragma unroll
    for (int ks2 = 0; ks2 < 2; ++ks2){
      bf16x8_t af[2], bf[4];
#pragma unroll
      for (int i = 0; i < 2; ++i){
        const int ra = wm*32 + i*16 + lr;
        const int lq = ks2*4 + g;
        af[i] = *(bf16x8_t*)&As[ra*64 + (lq ^ (ra&7))*8];
      }
#pragma unroll
      for (int j = 0; j < 4; ++j){
        const int rb = wn*64 + j*16 + lr;
        const int lq = ks2*4 + g;
        bf[j] = *(bf16x8_t*)&Ws[rb*64 + (lq ^ (rb&7))*8];
      }
#pragma unroll
      for (int i = 0; i < 2; ++i)
#pragma unroll
        for (int j = 0; j < 4; ++j)
          acc[i][j] = __builtin_amdgcn_mfma_f32_16x16x32_bf16(af[i], bf[j], acc[i][j], 0, 0, 0);
    }
  }
#pragma unroll
  for (int i = 0; i < 2; ++i)
#pragma unroll
    for (int j = 0; j < 4; ++j)
#pragma unroll
      for (int r = 0; r < 4; ++r){
        const int row = m0 + wm*32 + i*16 + g*4 + r;
        const int col = n0 + wn*64 + j*16 + lr;
        float v = acc[i][j][r] + bias[col];
        if (EPI == 2) v = v * 0.5f * (1.0f + erff(v * 0.70710678118654752440f));
        C[(size_t)row*N + col] = (__bf16)v;
      }
}

// ------------------------------------------------- combine: residual+LN (validated; NSPLIT unrolled)
// MODE 0: LN; MODE 1: LN with pos added to LN input; MODE 2: no LN, emit bf16 copy of x.
template<int MODE, int NSPLIT>
__global__ __launch_bounds__(256) void comb_res_ln(const float* __restrict__ parts,
                                                   const float* __restrict__ bias,
                                                   const float* __restrict__ pos,
                                                   const float* __restrict__ lw,
                                                   const float* __restrict__ lb,
                                                   float* __restrict__ x,
                                                   __bf16* __restrict__ xn){
  const int tok = blockIdx.x, gi = tok & 127, t = threadIdx.x;
  const int lane = t & 63, wv = t >> 6;
  float v[4];
#pragma unroll
  for (int j = 0; j < 4; ++j){
    const int d = t + j*256;
    const size_t idx = (size_t)tok*1024 + d;
    float s = 0;
#pragma unroll
    for (int z = 0; z < NSPLIT; ++z) s += parts[(size_t)z*524288 + idx];
    float val = x[idx] + s + bias[d];
    x[idx] = val;
    v[j] = val;
  }
  if (MODE == 2){
#pragma unroll
    for (int j = 0; j < 4; ++j){
      const int d = t + j*256;
      xn[(size_t)tok*1024 + d] = (__bf16)v[j];
    }
    return;
  }
  float u[4];
#pragma unroll
  for (int j = 0; j < 4; ++j){
    const int d = t + j*256;
    u[j] = v[j] + (MODE == 1 ? pos[gi*1024 + d] : 0.0f);
  }
  __shared__ float r1[4], r2[4];
  float s1 = wredsum(u[0]+u[1]+u[2]+u[3]);
  if (lane == 0) r1[wv] = s1;
  __syncthreads();
  const float mean = (r1[0]+r1[1]+r1[2]+r1[3]) * (1.0f/1024.0f);
  float sq = 0;
#pragma unroll
  for (int j = 0; j < 4; ++j){ float d0 = u[j]-mean; sq += d0*d0; }
  sq = wredsum(sq);
  if (lane == 0) r2[wv] = sq;
  __syncthreads();
  const float var = (r2[0]+r2[1]+r2[2]+r2[3]) * (1.0f/1024.0f);
  const float rs = rsqrtf(var + 1e-5f);
#pragma unroll
  for (int j = 0; j < 4; ++j){
    const int d = t + j*256;
    xn[(size_t)tok*1024 + d] = (__bf16)((u[j]-mean)*rs*lw[d] + lb[d]);
  }
}

// ------------------------------------------------- fused attention v2 + piggybacked weight conv
__global__ __launch_bounds__(256) void attn_fused(const __bf16* __restrict__ qkv,
                                                  __bf16* __restrict__ O,
                                                  const float* __restrict__ cs0,
                                                  const float* __restrict__ cs1,
                                                  const float* __restrict__ cs2,
                                                  const float* __restrict__ cs3,
                                                  __bf16* __restrict__ cdst,
                                                  int nch){
  if (blockIdx.x >= 64){
    const int t = (blockIdx.x - 64)*256 + threadIdx.x;
    if (t < nch){
      const size_t i = (size_t)t*8;
      const float* src;
      if (cs1 == nullptr){
        src = cs0 + i;
      } else {
        if (i < 3145728)       src = cs0 + i;
        else if (i < 4194304)  src = cs1 + (i-3145728);
        else if (i < 8388608)  src = cs2 + (i-4194304);
        else                   src = cs3 + (i-8388608);
      }
      float4 a = *(const float4*)src, bq = *(const float4*)(src+4);
      *(bf16x8_t*)(cdst + i) = pack8(a, bq);
    }
    return;
  }
  const int bh = blockIdx.x >> 1, half = blockIdx.x & 1;
  const int b = bh>>3, h = bh&7;
  const int tid = threadIdx.x, w = tid>>6, lane = tid&63;
  const int lr = lane&15, g = lane>>4;
  __shared__ __bf16 vt[128*128];    // V^T swizzled
  __shared__ __bf16 pl[4*2048];     // per-wave P (16x128), swizzled
  {
    const int n = tid >> 1, kh = tid & 1;
    const __bf16* vbase = qkv + (size_t)(b*128)*3072 + 2048 + h*128 + n;
#pragma unroll
    for (int jb = 0; jb < 8; ++jb){
      bf16x8_t pk;
#pragma unroll
      for (int e = 0; e < 8; ++e) pk[e] = vbase[(size_t)(kh*64 + jb*8 + e)*3072];
      const int cb = kh*8 + jb;
      *(bf16x8_t*)&vt[n*128 + ((cb ^ (n&7)) * 8)] = pk;
    }
  }
  const __bf16* qbase = qkv + (size_t)(b*128)*3072 + h*128;
  const __bf16* kbase = qbase + 1024;
  const int qrow0 = half*64 + w*16;
  f32x4_t acc[8] = {};
#pragma unroll
  for (int ks = 0; ks < 4; ++ks){
    bf16x8_t aq, bk[8];
    aq = *(const bf16x8_t*)(qbase + (size_t)(qrow0 + lr)*3072 + ks*32 + g*8);
#pragma unroll
    for (int j = 0; j < 8; ++j)
      bk[j] = *(const bf16x8_t*)(kbase + (size_t)(j*16 + lr)*3072 + ks*32 + g*8);
#pragma unroll
    for (int j = 0; j < 8; ++j)
      acc[j] = __builtin_amdgcn_mfma_f32_16x16x32_bf16(aq, bk[j], acc[j], 0, 0, 0);
  }
  __syncthreads();
  const float scale = 0.088388347648318447f;  // 1/sqrt(128)
#pragma unroll
  for (int r = 0; r < 4; ++r){
    const int row = g*4 + r;
    float sv[8];
    float mx = -1e30f;
#pragma unroll
    for (int j = 0; j < 8; ++j){ sv[j] = acc[j][r]*scale; mx = fmaxf(mx, sv[j]); }
#pragma unroll
    for (int o = 1; o < 16; o <<= 1) mx = fmaxf(mx, __shfl_xor(mx, o, 64));
    float s = 0;
#pragma unroll
    for (int j = 0; j < 8; ++j){ sv[j] = expf(sv[j]-mx); s += sv[j]; }
#pragma unroll
    for (int o = 1; o < 16; o <<= 1) s += __shfl_xor(s, o, 64);
    const float inv = 1.0f/s;
#pragma unroll
    for (int j = 0; j < 8; ++j){
      const int col = j*16 + lr;
      const int slot = (col>>3) ^ (row&7);
      pl[w*2048 + row*128 + slot*8 + (lr&7)] = (__bf16)(sv[j]*inv);
    }
  }
  __syncthreads();
  f32x4_t acc2[8] = {};
#pragma unroll
  for (int ks = 0; ks < 4; ++ks){
    bf16x8_t ap, bv[8];
    {
      const int row = lr;
      const int slot = (ks*4 + g) ^ (row&7);
      ap = *(bf16x8_t*)&pl[w*2048 + row*128 + slot*8];
    }
#pragma unroll
    for (int j = 0; j < 8; ++j){
      const int rowv = j*16 + lr;
      const int cb = ks*4 + g;
      bv[j] = *(bf16x8_t*)&vt[rowv*128 + ((cb ^ (rowv&7))*8)];
    }
#pragma unroll
    for (int j = 0; j < 8; ++j)
      acc2[j] = __builtin_amdgcn_mfma_f32_16x16x32_bf16(ap, bv[j], acc2[j], 0, 0, 0);
  }
#pragma unroll
  for (int j = 0; j < 8; ++j)
#pragma unroll
    for (int r = 0; r < 4; ++r){
      const int row = qrow0 + g*4 + r;
      const int col = j*16 + lr;
      O[(size_t)(b*128+row)*1024 + h*128 + col] = (__bf16)acc2[j][r];
    }
}

// ------------------------------------------------- head: c1 combine + BN + ReLU + c2 GEMV + centers
__global__ __launch_bounds__(256) void head_kernel(const float* __restrict__ parts,
                                                   const float* __restrict__ c1b,
                                                   const float* __restrict__ bnm,
                                                   const float* __restrict__ bnv,
                                                   const float* __restrict__ bng,
                                                   const float* __restrict__ bnb,
                                                   const float* __restrict__ c2w,
                                                   const float* __restrict__ c2b,
                                                   const float* __restrict__ centers,
                                                   float* __restrict__ out){
  const int tok = blockIdx.x, t = threadIdx.x;
  const int wv = t >> 6, lane = t & 63;
  __shared__ float hrow[1024];
#pragma unroll
  for (int j = 0; j < 4; ++j){
    const int d = t + j*256;
    const size_t idx = (size_t)tok*1024 + d;
    float s = 0;
#pragma unroll
    for (int z = 0; z < 8; ++z) s += parts[(size_t)z*524288 + idx];
    float v = s + c1b[d];
    v = (v - bnm[d]) * rsqrtf(bnv[d] + 1e-5f) * bng[d] + bnb[d];
    hrow[d] = fmaxf(v, 0.0f);
  }
  __syncthreads();
  for (int i = 0; i < 24; ++i){
    const int n = wv*24 + i;
    const float* wp = c2w + (size_t)n*1024;
    float s = 0;
#pragma unroll 4
    for (int j = 0; j < 16; ++j){
      const int k = lane + j*64;
      s += hrow[k] * wp[k];
    }
    s = wredsum(s);
    if (lane == 0) out[(size_t)tok*96 + n] = s + c2b[n] + centers[tok*3 + (n % 3)];
  }
}

// =================================================================
extern "C" void kernel_launch(void* const* d_in, const int* in_sizes, int n_in,
                              void* d_out, int out_size, void* d_ws, size_t ws_size,
                              hipStream_t stream){
  const float* lh   = (const float*)d_in[0];
  const float* pc   = (const float*)d_in[1];
  const float* fpw  = (const float*)d_in[2];
  const float* fpb  = (const float*)d_in[3];
  const float* spw  = (const float*)d_in[4];
  const float* spb  = (const float*)d_in[5];
  const float* pos  = (const float*)d_in[6];
  const float* ln1w = (const float*)d_in[7];
  const float* ln1b = (const float*)d_in[8];
  const float* inw  = (const float*)d_in[9];
  const float* inb  = (const float*)d_in[10];
  const float* outw = (const float*)d_in[11];
  const float* outb = (const float*)d_in[12];
  const float* ln2w = (const float*)d_in[13];
  const float* ln2b = (const float*)d_in[14];
  const float* w1   = (const float*)d_in[15];
  const float* b1   = (const float*)d_in[16];
  const float* w2   = (const float*)d_in[17];
  const float* b2   = (const float*)d_in[18];
  const float* c1w  = (const float*)d_in[19];
  const float* c1b  = (const float*)d_in[20];
  const float* bng  = (const float*)d_in[21];
  const float* bnbt = (const float*)d_in[22];
  const float* bnm  = (const float*)d_in[23];
  const float* bnv  = (const float*)d_in[24];
  const float* c2w  = (const float*)d_in[25];
  const float* c2b  = (const float*)d_in[26];
  float* out = (float*)d_out;

  // ---- workspace layout ----
  float* f = (float*)d_ws;
  float* parts = f;              f += 16*524288;  // split-K fp32 partials (32 MB)
  float* part  = f;              f += 131072;
  float* mlh   = f;              f += 16384;
  float* agg   = f;              f += 4096;
  float* x     = f;              f += 524288;     // residual stream fp32
  float* cent  = f;              f += 2048;       // centers (+pad)
  __bf16* bfp = (__bf16*)f;
  __bf16* xn   = bfp;            bfp += 524288;   // LN out bf16
  __bf16* qkv  = bfp;            bfp += 1572864;
  __bf16* obuf = bfp;            bfp += 524288;
  __bf16* hbf  = bfp;            bfp += 2097152;  // MLP hidden bf16
  __bf16* xbf  = bfp;            bfp += 524288;   // bf16 copy of final x
  __bf16* wbf  = bfp;            bfp += 51380224; // all weights bf16 (4 layers + c1 at +50331648)

  partial_kernel<<<dim3(16,8,4), 256, 0, stream>>>(lh, part);
  combine_kernel<<<64, 256, 0, stream>>>(part, mlh);
  agg_kernel<<<1024, 256, 0, stream>>>(mlh, fpw, fpb, agg);
  fused_front<<<2564, 1024, 0, stream>>>(pc, cent, agg, spw, spb, x,
                                         inw, outw, w1, w2, wbf);
  ln_kernel<<<512, 256, 0, stream>>>(x, pos, ln1w, ln1b, xn);

  for (int l = 0; l < 4; ++l){
    const __bf16* wl = wbf + (size_t)l*12582912;
    // qkv: 512x3072x1024 full-K, 64-row tile (192 blocks, 16 steps), bias fused -> bf16
    gemm64f<0><<<dim3(24,8), 256, 0, stream>>>(xn, wl, inb + l*3072, qkv, 512, 3072, 1024);
    // attn (64 blocks) + piggybacked conversion of next layer's weights (or c1 at l=3)
    if (l < 3)
      attn_fused<<<64 + 6144, 256, 0, stream>>>(qkv, obuf,
          inw + (size_t)(l+1)*3145728, outw + (size_t)(l+1)*1048576,
          w1 + (size_t)(l+1)*4194304, w2 + (size_t)(l+1)*4194304,
          wbf + (size_t)(l+1)*12582912, 1572864);
    else
      attn_fused<<<64 + 512, 256, 0, stream>>>(qkv, obuf,
          c1w, nullptr, nullptr, nullptr, wbf + 50331648, 131072);
    // attn-out: 512x1024x1024, split-8 (256 blocks, 2 steps)
    gemm_sk<<<dim3(8,4,8), 256, 0, stream>>>(obuf, wl + 3145728, parts, 512, 1024, 1024, 128);
    comb_res_ln<0,8><<<512, 256, 0, stream>>>(parts, outb + l*1024, nullptr,
                                              ln2w + l*1024, ln2b + l*1024, x, xn);
    // mlp1: 512x4096x1024 full-K, 64-row tile (256 blocks, 16 steps), bias+GELU fused -> bf16
    gemm64f<2><<<dim3(32,8), 256, 0, stream>>>(xn, wl + 4194304, b1 + l*4096, hbf, 512, 4096, 1024);
    // mlp2: 512x1024x4096, split-8 (256 blocks, 8 steps)
    gemm_sk<<<dim3(8,4,8), 256, 0, stream>>>(hbf, wl + 8388608, parts, 512, 1024, 4096, 512);
    if (l < 3)
      comb_res_ln<1,8><<<512, 256, 0, stream>>>(parts, b2 + l*1024, pos,
                                                ln1w + (l+1)*1024, ln1b + (l+1)*1024, x, xn);
    else
      comb_res_ln<2,8><<<512, 256, 0, stream>>>(parts, b2 + l*1024, nullptr,
                                                nullptr, nullptr, x, xbf);
  }

  // c1: 512x1024x1024, split-8 (256 blocks, 2 steps); head fuses combine+BN+ReLU+c2+centers
  gemm_sk<<<dim3(8,4,8), 256, 0, stream>>>(xbf, wbf + 50331648, parts, 512, 1024, 1024, 128);
  head_kernel<<<512, 256, 0, stream>>>(parts, c1b, bnm, bnv, bng, bnbt, c2w, c2b, cent, out);
}